// Round 3
// baseline (433.087 us; speedup 1.0000x reference)
//
#include <hip/hip_runtime.h>

typedef unsigned short u16;
typedef unsigned int   u32;
typedef float f32x2 __attribute__((ext_vector_type(2)));

// ---- bf16 helpers (RNE pack, bit-shift unpack) ----
__device__ __forceinline__ u16 f2b(float f) {
    u32 u = __float_as_uint(f);
    return (u16)((u + 0x7fffu + ((u >> 16) & 1u)) >> 16);
}
__device__ __forceinline__ u32 pack2f(float a, float b) {
    return (u32)f2b(a) | ((u32)f2b(b) << 16);
}
__device__ __forceinline__ f32x2 unpk2(u32 w) {   // {lo bf16, hi bf16} -> f32 pair
    f32x2 r;
    r[0] = __uint_as_float(w << 16);
    r[1] = __uint_as_float(w & 0xffff0000u);
    return r;
}
// channel permutation (involution): slot cc holds original channel perm(cc)
__device__ __forceinline__ int permc(int c) { return ((c & 7) << 3) | (c >> 3); }

__device__ __forceinline__ f32x2 bc2(float x) { f32x2 r; r[0] = x; r[1] = x; return r; }
__device__ __forceinline__ f32x2 mk2(float a, float b) { f32x2 r; r[0] = a; r[1] = b; return r; }

// DPP cross-lane (VALU pipe, no LDS/waitcnt): reduce within aligned 8-lane groups
template<int CTRL>
__device__ __forceinline__ float dppf(float x) {
    return __int_as_float(__builtin_amdgcn_update_dpp(0, __float_as_int(x), CTRL, 0xf, 0xf, true));
}
__device__ __forceinline__ float gsum8(float x) {
    x += dppf<0xB1>(x);    // quad_perm [1,0,3,2]  (xor 1)
    x += dppf<0x4E>(x);    // quad_perm [2,3,0,1]  (xor 2)
    x += dppf<0x141>(x);   // row_half_mirror      (xor 7 within 8 => cross-quad)
    return x;
}
__device__ __forceinline__ float gmax8(float x) {
    x = fmaxf(x, dppf<0xB1>(x));
    x = fmaxf(x, dppf<0x4E>(x));
    x = fmaxf(x, dppf<0x141>(x));
    return x;
}

// ============ prep: pair-interleaved linear_p stage-2 params ============
// blob[(l8*4+p)*8] = {A0e,A0o, A1e,A1o, A2e,A2o, Be,Bo}, ce=16p+l8, co=ce+8
__global__ void prep_kernel(const float* __restrict__ p_w2,
                            const float* __restrict__ p_b2,
                            float* __restrict__ blob)
{
    int tid = threadIdx.x;
    if (tid < 32) {
        int l8 = tid >> 2, p = tid & 3;
        int ce = 16 * p + l8, co = ce + 8;
        float* b = blob + tid * 8;
        b[0] = p_w2[ce];       b[1] = p_w2[co];
        b[2] = p_w2[64 + ce];  b[3] = p_w2[64 + co];
        b[4] = p_w2[128 + ce]; b[5] = p_w2[128 + co];
        b[6] = p_b2[ce];       b[7] = p_b2[co];
    }
}

// ================= Kernel 1: q/k/v projections =================
// qt [n*64  + cc]      = q[n][perm(cc)]   (bf16)
// kvt[n*128 + cc]      = k[n][perm(cc)]   (bf16)
// kvt[n*128 + 64 + cc] = v[n][perm(cc)]   (bf16)
// 128 rows/block, 4 rows/thread; feat transposed in LDS (stride 132 = conflict-free reads)
__global__ __launch_bounds__(256) void qkv_kernel(
    const float* __restrict__ feat,
    const float* __restrict__ Wq, const float* __restrict__ bq,
    const float* __restrict__ Wk, const float* __restrict__ bk,
    const float* __restrict__ Wv, const float* __restrict__ bv,
    u16* __restrict__ qt, u16* __restrict__ kvt)
{
    __shared__ u16   wlb[3][64][64];   // 24KB, bf16 weights, cols permuted
    __shared__ float ft[64][132];      // 33.8KB, ft[channel][row], 128 rows used
    const int t = threadIdx.x;
    const int rowbase = blockIdx.x * 128;

    {
        const float* Ws[3] = {Wq, Wk, Wv};
#pragma unroll
        for (int mm = 0; mm < 3; mm++) {
            for (int e = t; e < 1024; e += 256) {
                int i = e >> 4, c4 = (e & 15) * 4;
                float4 w = *(const float4*)&Ws[mm][i * 64 + c4];
                wlb[mm][i][permc(c4 + 0)] = f2b(w.x);
                wlb[mm][i][permc(c4 + 1)] = f2b(w.y);
                wlb[mm][i][permc(c4 + 2)] = f2b(w.z);
                wlb[mm][i][permc(c4 + 3)] = f2b(w.w);
            }
        }
    }
    for (int e = t; e < 2048; e += 256) {          // 8192 floats of feat
        int r = e >> 4, c4 = (e & 15) * 4;
        float4 v = *(const float4*)&feat[(size_t)(rowbase + r) * 64 + c4];
        ft[c4 + 0][r] = v.x;
        ft[c4 + 1][r] = v.y;
        ft[c4 + 2][r] = v.z;
        ft[c4 + 3][r] = v.w;
    }
    __syncthreads();

    const int rg = t >> 3;         // rows rg*4 .. rg*4+3
    const int q8 = t & 7;
    const int c0 = q8 * 8;         // 8 consecutive permuted slots

    f32x2 acc[3][4][4];            // [matrix][row][pair]; pair = channels {16p+q8, 16p+8+q8}
    {
        const float* Bs[3] = {bq, bk, bv};
#pragma unroll
        for (int m = 0; m < 3; m++)
#pragma unroll
            for (int p = 0; p < 4; p++) {
                f32x2 b = mk2(Bs[m][16 * p + q8], Bs[m][16 * p + 8 + q8]);
#pragma unroll
                for (int r = 0; r < 4; r++) acc[m][r][p] = b;
            }
    }

#pragma unroll 2
    for (int i = 0; i < 64; i++) {
        float4 f4 = *(const float4*)&ft[i][rg * 4];
        f32x2 fb[4] = {bc2(f4.x), bc2(f4.y), bc2(f4.z), bc2(f4.w)};
#pragma unroll
        for (int m = 0; m < 3; m++) {
            uint4 wv = *(const uint4*)&wlb[m][i][c0];
            f32x2 w0 = unpk2(wv.x), w1 = unpk2(wv.y), w2 = unpk2(wv.z), w3 = unpk2(wv.w);
#pragma unroll
            for (int r = 0; r < 4; r++) {
                acc[m][r][0] += fb[r] * w0;
                acc[m][r][1] += fb[r] * w1;
                acc[m][r][2] += fb[r] * w2;
                acc[m][r][3] += fb[r] * w3;
            }
        }
    }

#pragma unroll
    for (int r = 0; r < 4; r++) {
        int row = rowbase + rg * 4 + r;
        uint4 oq, ok, ov;
        oq.x = pack2f(acc[0][r][0][0], acc[0][r][0][1]);
        oq.y = pack2f(acc[0][r][1][0], acc[0][r][1][1]);
        oq.z = pack2f(acc[0][r][2][0], acc[0][r][2][1]);
        oq.w = pack2f(acc[0][r][3][0], acc[0][r][3][1]);
        ok.x = pack2f(acc[1][r][0][0], acc[1][r][0][1]);
        ok.y = pack2f(acc[1][r][1][0], acc[1][r][1][1]);
        ok.z = pack2f(acc[1][r][2][0], acc[1][r][2][1]);
        ok.w = pack2f(acc[1][r][3][0], acc[1][r][3][1]);
        ov.x = pack2f(acc[2][r][0][0], acc[2][r][0][1]);
        ov.y = pack2f(acc[2][r][1][0], acc[2][r][1][1]);
        ov.z = pack2f(acc[2][r][2][0], acc[2][r][2][1]);
        ov.w = pack2f(acc[2][r][3][0], acc[2][r][3][1]);
        *(uint4*)&qt [(size_t)row * 64 + c0]       = oq;
        *(uint4*)&kvt[(size_t)row * 128 + c0]      = ok;
        *(uint4*)&kvt[(size_t)row * 128 + 64 + c0] = ov;
    }
}

// ================= Kernel 2: fused gather + attention =================
// 8 lanes/point; lane l8 owns channel pairs {16p+l8, 16p+8+l8}, softmax column = l8.
__global__ __launch_bounds__(256, 4) void attn_kernel(
    const float* __restrict__ point,
    const int*   __restrict__ idx,
    const u16*   __restrict__ qt,
    const u16*   __restrict__ kvt,
    const float* __restrict__ blob,
    const float* __restrict__ p_w1,   const float* __restrict__ p_b1,
    const float* __restrict__ p_bn_g, const float* __restrict__ p_bn_b,
    const float* __restrict__ p_bn_m, const float* __restrict__ p_bn_v,
    const float* __restrict__ w_bn1_g, const float* __restrict__ w_bn1_b,
    const float* __restrict__ w_bn1_m, const float* __restrict__ w_bn1_v,
    const float* __restrict__ w_w1,    const float* __restrict__ w_b1,
    const float* __restrict__ w_bn2_g, const float* __restrict__ w_bn2_b,
    const float* __restrict__ w_bn2_m, const float* __restrict__ w_bn2_v,
    const float* __restrict__ w_w2,    const float* __restrict__ w_b2,
    float* __restrict__ out)
{
    const int t  = threadIdx.x;
    const int l8 = t & 7;
    const int n  = blockIdx.x * 32 + (t >> 3);
    const float EPS = 1e-5f;

    // ---- wave-uniform params (SGPR) ----
    float pw1[9];
#pragma unroll
    for (int i = 0; i < 9; i++) pw1[i] = p_w1[i];
    float pb1b[3], pbs[3], pbh[3];
#pragma unroll
    for (int a = 0; a < 3; a++) {
        float s = p_bn_g[a] * rsqrtf(p_bn_v[a] + EPS);
        pb1b[a] = p_b1[a];
        pbs[a]  = s;
        pbh[a]  = p_bn_b[a] - p_bn_m[a] * s;
    }
    float b2s[8], b2hh[8];   // bn2 scale; offset with w_b1 folded in
#pragma unroll
    for (int h = 0; h < 8; h++) {
        float s = w_bn2_g[h] * rsqrtf(w_bn2_v[h] + EPS);
        b2s[h]  = s;
        b2hh[h] = (w_bn2_b[h] - w_bn2_m[h] * s) + w_b1[h] * s;
    }
    // ---- per-lane params ----
    float ww2c[8];
#pragma unroll
    for (int h = 0; h < 8; h++) ww2c[h] = w_w2[h * 8 + l8];
    const float wb2l = w_b2[l8];

    const float4* pbase = (const float4*)(blob + l8 * 32);
    const float*  w1b   = w_w1 + l8 * 8;

    // bn1 scale + offset with q folded: w = relu((k+pj)*s + (h - q*s))
    f32x2 s2[4], qh2[4];
    {
        uint4 qr = *(const uint4*)&qt[(size_t)n * 64 + l8 * 8];
        const u32* qw = (const u32*)&qr;
#pragma unroll
        for (int p = 0; p < 4; p++) {
            int ce = 16 * p + l8, co = ce + 8;
            float se = w_bn1_g[ce] * rsqrtf(w_bn1_v[ce] + EPS);
            float so = w_bn1_g[co] * rsqrtf(w_bn1_v[co] + EPS);
            float he = w_bn1_b[ce] - w_bn1_m[ce] * se;
            float ho = w_bn1_b[co] - w_bn1_m[co] * so;
            f32x2 q2 = unpk2(qw[p]);
            s2[p]  = mk2(se, so);
            qh2[p] = mk2(he - q2[0] * se, ho - q2[1] * so);
        }
    }

    const float px = point[n * 3], py = point[n * 3 + 1], pz = point[n * 3 + 2];
    f32x2 acc2[4];
#pragma unroll
    for (int p = 0; p < 4; p++) acc2[p] = mk2(0.f, 0.f);

    // 1-iter lookahead pipeline on gathers
    int j0 = idx[(size_t)n * 16];
    const u16* kv0 = kvt + (size_t)j0 * 128 + l8 * 8;
    uint4 kr = *(const uint4*)kv0;
    uint4 vr = *(const uint4*)(kv0 + 64);
    float jx = point[j0 * 3], jy = point[j0 * 3 + 1], jz = point[j0 * 3 + 2];

    for (int kk = 0; kk < 16; kk++) {
        int kk1 = kk < 15 ? kk + 1 : 15;
        int jn = idx[(size_t)n * 16 + kk1];
        const u16* kvn = kvt + (size_t)jn * 128 + l8 * 8;
        uint4 krn = *(const uint4*)kvn;
        uint4 vrn = *(const uint4*)(kvn + 64);
        float jxn = point[jn * 3], jyn = point[jn * 3 + 1], jzn = point[jn * 3 + 2];

        // linear_p stage 1 (3->3, BN, ReLU)
        float dx = jx - px, dy = jy - py, dz = jz - pz;
        float t0 = fmaxf(0.f, fmaf(fmaf(dz, pw1[6], fmaf(dy, pw1[3], fmaf(dx, pw1[0], pb1b[0]))), pbs[0], pbh[0]));
        float t1 = fmaxf(0.f, fmaf(fmaf(dz, pw1[7], fmaf(dy, pw1[4], fmaf(dx, pw1[1], pb1b[1]))), pbs[1], pbh[1]));
        float t2 = fmaxf(0.f, fmaf(fmaf(dz, pw1[8], fmaf(dy, pw1[5], fmaf(dx, pw1[2], pb1b[2]))), pbs[2], pbh[2]));
        f32x2 tp0 = bc2(t0), tp1 = bc2(t1), tp2 = bc2(t2);

        const u32* kw = (const u32*)&kr;
        f32x2 partial[4];
#pragma unroll
        for (int hp = 0; hp < 4; hp++) partial[hp] = mk2(0.f, 0.f);
        f32x2 pjs[4];

#pragma unroll
        for (int p = 0; p < 4; p++) {
            float4 A = pbase[2 * p], B = pbase[2 * p + 1];
            f32x2 P0 = mk2(A.x, A.y), P1 = mk2(A.z, A.w);
            f32x2 P2 = mk2(B.x, B.y), PB = mk2(B.z, B.w);
            f32x2 pj = PB + tp0 * P0 + tp1 * P1 + tp2 * P2;   // linear_p stage 2, channel pair
            pjs[p] = pj;
            f32x2 kf = unpk2(kw[p]);
            f32x2 w2 = (kf + pj) * s2[p] + qh2[p];            // bn1 with q folded
            w2[0] = fmaxf(w2[0], 0.f);
            w2[1] = fmaxf(w2[1], 0.f);
            f32x2 we = bc2(w2[0]), wo = bc2(w2[1]);
            float4 e0 = *(const float4*)(w1b + 128 * p);
            float4 e1 = *(const float4*)(w1b + 128 * p + 4);
            float4 o0 = *(const float4*)(w1b + 128 * p + 64);
            float4 o1 = *(const float4*)(w1b + 128 * p + 68);
            partial[0] += we * mk2(e0.x, e0.y) + wo * mk2(o0.x, o0.y);
            partial[1] += we * mk2(e0.z, e0.w) + wo * mk2(o0.z, o0.w);
            partial[2] += we * mk2(e1.x, e1.y) + wo * mk2(o1.x, o1.y);
            partial[3] += we * mk2(e1.z, e1.w) + wo * mk2(o1.z, o1.w);
        }
        // 64 -> 8 reduce across the 8-lane group (DPP, VALU pipe)
#pragma unroll
        for (int hp = 0; hp < 4; hp++) {
            partial[hp][0] = gsum8(partial[hp][0]);
            partial[hp][1] = gsum8(partial[hp][1]);
        }
        // relu(bn2(.)) @ w_w2 -> this lane's softmax logit (c2 = l8)
        float y = wb2l;
#pragma unroll
        for (int h = 0; h < 8; h++) {
            float ph = partial[h >> 1][h & 1];
            float wb = fmaxf(0.f, fmaf(ph, b2s[h], b2hh[h]));
            y = fmaf(wb, ww2c[h], y);
        }
        // softmax over the 8 lanes of the group
        float mx = gmax8(y);
        float e  = __expf(y - mx);
        float ssum = gsum8(e);
        float sm = e * __builtin_amdgcn_rcpf(ssum);
        f32x2 sm2 = bc2(sm);

        const u32* vw = (const u32*)&vr;
#pragma unroll
        for (int p = 0; p < 4; p++) {
            f32x2 vp = unpk2(vw[p]) + pjs[p];
            acc2[p] += sm2 * vp;
        }

        kr = krn; vr = vrn; jx = jxn; jy = jyn; jz = jzn;
    }

#pragma unroll
    for (int p = 0; p < 4; p++) {
        out[(size_t)n * 64 + 16 * p + l8]     = acc2[p][0];
        out[(size_t)n * 64 + 16 * p + 8 + l8] = acc2[p][1];
    }
}

extern "C" void kernel_launch(void* const* d_in, const int* in_sizes, int n_in,
                              void* d_out, int out_size, void* d_ws, size_t ws_size,
                              hipStream_t stream)
{
    const float* point   = (const float*)d_in[0];
    const float* feat    = (const float*)d_in[1];
    const int*   idx     = (const int*)d_in[2];
    const float* Wq      = (const float*)d_in[3];
    const float* bq      = (const float*)d_in[4];
    const float* Wk      = (const float*)d_in[5];
    const float* bk      = (const float*)d_in[6];
    const float* Wv      = (const float*)d_in[7];
    const float* bv      = (const float*)d_in[8];
    const float* p_w1    = (const float*)d_in[9];
    const float* p_b1    = (const float*)d_in[10];
    const float* p_bn_g  = (const float*)d_in[11];
    const float* p_bn_b  = (const float*)d_in[12];
    const float* p_bn_m  = (const float*)d_in[13];
    const float* p_bn_v  = (const float*)d_in[14];
    const float* p_w2    = (const float*)d_in[15];
    const float* p_b2    = (const float*)d_in[16];
    const float* w_bn1_g = (const float*)d_in[17];
    const float* w_bn1_b = (const float*)d_in[18];
    const float* w_bn1_m = (const float*)d_in[19];
    const float* w_bn1_v = (const float*)d_in[20];
    const float* w_w1    = (const float*)d_in[21];
    const float* w_b1    = (const float*)d_in[22];
    const float* w_bn2_g = (const float*)d_in[23];
    const float* w_bn2_b = (const float*)d_in[24];
    const float* w_bn2_m = (const float*)d_in[25];
    const float* w_bn2_v = (const float*)d_in[26];
    const float* w_w2    = (const float*)d_in[27];
    const float* w_b2    = (const float*)d_in[28];
    float* out = (float*)d_out;

    const int N = in_sizes[0] / 3;   // 65536

    // workspace: kvt N*128 bf16 (16.8MB) | qt N*64 bf16 (8.4MB) | blob 256 f32
    u16*   kvt  = (u16*)d_ws;
    u16*   qt   = (u16*)d_ws + (size_t)N * 128;
    float* blob = (float*)((u16*)d_ws + (size_t)N * 192);

    prep_kernel<<<1, 32, 0, stream>>>(p_w2, p_b2, blob);
    qkv_kernel<<<N / 128, 256, 0, stream>>>(feat, Wq, bq, Wk, bk, Wv, bv, qt, kvt);
    attn_kernel<<<N / 32, 256, 0, stream>>>(point, idx, qt, kvt, blob,
                                            p_w1, p_b1, p_bn_g, p_bn_b, p_bn_m, p_bn_v,
                                            w_bn1_g, w_bn1_b, w_bn1_m, w_bn1_v, w_w1, w_b1,
                                            w_bn2_g, w_bn2_b, w_bn2_m, w_bn2_v, w_w2, w_b2,
                                            out);
}

// Round 4
// 95.926 us; speedup vs baseline: 4.5148x; 4.5148x over previous
//
#include <hip/hip_runtime.h>

typedef unsigned short u16;
typedef unsigned int   u32;
typedef float f32x2 __attribute__((ext_vector_type(2)));

// ---- bf16 helpers (RNE pack, bit-shift unpack) ----
__device__ __forceinline__ u16 f2b(float f) {
    u32 u = __float_as_uint(f);
    return (u16)((u + 0x7fffu + ((u >> 16) & 1u)) >> 16);
}
__device__ __forceinline__ u32 pack2f(float a, float b) {
    return (u32)f2b(a) | ((u32)f2b(b) << 16);
}
__device__ __forceinline__ f32x2 unpk2(u32 w) {   // {lo bf16, hi bf16} -> f32 pair
    f32x2 r;
    r[0] = __uint_as_float(w << 16);
    r[1] = __uint_as_float(w & 0xffff0000u);
    return r;
}
// channel permutation (involution): slot cc holds original channel perm(cc)
__device__ __forceinline__ int permc(int c) { return ((c & 7) << 3) | (c >> 3); }

__device__ __forceinline__ f32x2 bc2(float x) { f32x2 r; r[0] = x; r[1] = x; return r; }
__device__ __forceinline__ f32x2 mk2(float a, float b) { f32x2 r; r[0] = a; r[1] = b; return r; }

// packed bf16 dot: c += a.lo*b.lo + a.hi*b.hi  (VOP3P, all operands single VGPRs)
__device__ __forceinline__ void dot2bf(float& c, u32 a, u32 b) {
    asm("v_dot2_f32_bf16 %0, %1, %2, %0" : "+v"(c) : "v"(a), "v"(b));
}
// single-instruction f32x2 -> packed bf16 (lo = first operand)
__device__ __forceinline__ u32 cvtpk(float lo, float hi) {
    u32 r;
    asm("v_cvt_pk_bf16_f32 %0, %1, %2" : "=v"(r) : "v"(lo), "v"(hi));
    return r;
}

// DPP cross-lane (VALU pipe, no LDS/waitcnt): reduce within aligned 8-lane groups
template<int CTRL>
__device__ __forceinline__ float dppf(float x) {
    return __int_as_float(__builtin_amdgcn_update_dpp(0, __float_as_int(x), CTRL, 0xf, 0xf, true));
}
__device__ __forceinline__ float gsum8(float x) {
    x += dppf<0xB1>(x);    // quad_perm [1,0,3,2]  (xor 1)
    x += dppf<0x4E>(x);    // quad_perm [2,3,0,1]  (xor 2)
    x += dppf<0x141>(x);   // row_half_mirror      (cross-quad within 8)
    return x;
}
__device__ __forceinline__ float gmax8(float x) {
    x = fmaxf(x, dppf<0xB1>(x));
    x = fmaxf(x, dppf<0x4E>(x));
    x = fmaxf(x, dppf<0x141>(x));
    return x;
}

// ================= Kernel 1: q/k/v projections (unchanged, known-good) ========
__global__ __launch_bounds__(256) void qkv_kernel(
    const float* __restrict__ feat,
    const float* __restrict__ Wq, const float* __restrict__ bq,
    const float* __restrict__ Wk, const float* __restrict__ bk,
    const float* __restrict__ Wv, const float* __restrict__ bv,
    u16* __restrict__ qt, u16* __restrict__ kvt)
{
    __shared__ u16   wlb[3][64][64];   // 24KB, bf16 weights, cols permuted
    __shared__ float ft[64][132];      // ft[channel][row], 128 rows used
    const int t = threadIdx.x;
    const int rowbase = blockIdx.x * 128;

    {
        const float* Ws[3] = {Wq, Wk, Wv};
#pragma unroll
        for (int mm = 0; mm < 3; mm++) {
            for (int e = t; e < 1024; e += 256) {
                int i = e >> 4, c4 = (e & 15) * 4;
                float4 w = *(const float4*)&Ws[mm][i * 64 + c4];
                wlb[mm][i][permc(c4 + 0)] = f2b(w.x);
                wlb[mm][i][permc(c4 + 1)] = f2b(w.y);
                wlb[mm][i][permc(c4 + 2)] = f2b(w.z);
                wlb[mm][i][permc(c4 + 3)] = f2b(w.w);
            }
        }
    }
    for (int e = t; e < 2048; e += 256) {
        int r = e >> 4, c4 = (e & 15) * 4;
        float4 v = *(const float4*)&feat[(size_t)(rowbase + r) * 64 + c4];
        ft[c4 + 0][r] = v.x;
        ft[c4 + 1][r] = v.y;
        ft[c4 + 2][r] = v.z;
        ft[c4 + 3][r] = v.w;
    }
    __syncthreads();

    const int rg = t >> 3;
    const int q8 = t & 7;
    const int c0 = q8 * 8;

    f32x2 acc[3][4][4];
    {
        const float* Bs[3] = {bq, bk, bv};
#pragma unroll
        for (int m = 0; m < 3; m++)
#pragma unroll
            for (int p = 0; p < 4; p++) {
                f32x2 b = mk2(Bs[m][16 * p + q8], Bs[m][16 * p + 8 + q8]);
#pragma unroll
                for (int r = 0; r < 4; r++) acc[m][r][p] = b;
            }
    }

#pragma unroll 2
    for (int i = 0; i < 64; i++) {
        float4 f4 = *(const float4*)&ft[i][rg * 4];
        f32x2 fb[4] = {bc2(f4.x), bc2(f4.y), bc2(f4.z), bc2(f4.w)};
#pragma unroll
        for (int m = 0; m < 3; m++) {
            uint4 wv = *(const uint4*)&wlb[m][i][c0];
            f32x2 w0 = unpk2(wv.x), w1 = unpk2(wv.y), w2 = unpk2(wv.z), w3 = unpk2(wv.w);
#pragma unroll
            for (int r = 0; r < 4; r++) {
                acc[m][r][0] += fb[r] * w0;
                acc[m][r][1] += fb[r] * w1;
                acc[m][r][2] += fb[r] * w2;
                acc[m][r][3] += fb[r] * w3;
            }
        }
    }

#pragma unroll
    for (int r = 0; r < 4; r++) {
        int row = rowbase + rg * 4 + r;
        uint4 oq, ok, ov;
        oq.x = pack2f(acc[0][r][0][0], acc[0][r][0][1]);
        oq.y = pack2f(acc[0][r][1][0], acc[0][r][1][1]);
        oq.z = pack2f(acc[0][r][2][0], acc[0][r][2][1]);
        oq.w = pack2f(acc[0][r][3][0], acc[0][r][3][1]);
        ok.x = pack2f(acc[1][r][0][0], acc[1][r][0][1]);
        ok.y = pack2f(acc[1][r][1][0], acc[1][r][1][1]);
        ok.z = pack2f(acc[1][r][2][0], acc[1][r][2][1]);
        ok.w = pack2f(acc[1][r][3][0], acc[1][r][3][1]);
        ov.x = pack2f(acc[2][r][0][0], acc[2][r][0][1]);
        ov.y = pack2f(acc[2][r][1][0], acc[2][r][1][1]);
        ov.z = pack2f(acc[2][r][2][0], acc[2][r][2][1]);
        ov.w = pack2f(acc[2][r][3][0], acc[2][r][3][1]);
        *(uint4*)&qt [(size_t)row * 64 + c0]       = oq;
        *(uint4*)&kvt[(size_t)row * 128 + c0]      = ok;
        *(uint4*)&kvt[(size_t)row * 128 + 64 + c0] = ov;
    }
}

// ================= Kernel 2: fused gather + attention =================
// 8 lanes/point; lane l8 owns channel pairs {16p+l8, 16p+8+l8}; softmax col = l8.
// ALL loop-invariant params in registers (bf16-packed where big); zero global
// loads in the loop except the 4 gathers. DPP reduces on the VALU pipe.
__global__ __launch_bounds__(256) void attn_kernel(
    const float* __restrict__ point,
    const int*   __restrict__ idx,
    const u16*   __restrict__ qt,
    const u16*   __restrict__ kvt,
    const float* __restrict__ p_w1,   const float* __restrict__ p_b1,
    const float* __restrict__ p_bn_g, const float* __restrict__ p_bn_b,
    const float* __restrict__ p_bn_m, const float* __restrict__ p_bn_v,
    const float* __restrict__ p_w2,   const float* __restrict__ p_b2,
    const float* __restrict__ w_bn1_g, const float* __restrict__ w_bn1_b,
    const float* __restrict__ w_bn1_m, const float* __restrict__ w_bn1_v,
    const float* __restrict__ w_w1,    const float* __restrict__ w_b1,
    const float* __restrict__ w_bn2_g, const float* __restrict__ w_bn2_b,
    const float* __restrict__ w_bn2_m, const float* __restrict__ w_bn2_v,
    const float* __restrict__ w_w2,    const float* __restrict__ w_b2,
    float* __restrict__ out)
{
    const int t  = threadIdx.x;
    const int l8 = t & 7;
    const int n  = blockIdx.x * 32 + (t >> 3);
    const float EPS = 1e-5f;

    // ---- wave-uniform params (SGPR) ----
    // linear_p stage 1 with BN folded AND pre-scaled: t_a = relu(dot(d, pw1s[:,a]) + pbh2[a])
    float pw1s[9], pbh2[3];
#pragma unroll
    for (int a = 0; a < 3; a++) {
        float s = p_bn_g[a] * rsqrtf(p_bn_v[a] + EPS);
        float h = p_bn_b[a] - p_bn_m[a] * s;
        pbh2[a] = p_b1[a] * s + h;
#pragma unroll
        for (int i = 0; i < 3; i++) pw1s[i * 3 + a] = p_w1[i * 3 + a] * s;
    }
    float b2s[8], b2hh[8];   // bn2 scale; offset with w_b1 folded in
#pragma unroll
    for (int h = 0; h < 8; h++) {
        float s = w_bn2_g[h] * rsqrtf(w_bn2_v[h] + EPS);
        b2s[h]  = s;
        b2hh[h] = (w_bn2_b[h] - w_bn2_m[h] * s) + w_b1[h] * s;
    }

    // ---- per-lane register params (loaded ONCE) ----
    // linear_p stage 2, channel pairs ce=16p+l8, co=ce+8
    f32x2 P0[4], P1[4], P2[4], PB[4];
#pragma unroll
    for (int p = 0; p < 4; p++) {
        int ce = 16 * p + l8, co = ce + 8;
        P0[p] = mk2(p_w2[ce],       p_w2[co]);
        P1[p] = mk2(p_w2[64 + ce],  p_w2[64 + co]);
        P2[p] = mk2(p_w2[128 + ce], p_w2[128 + co]);
        PB[p] = mk2(p_b2[ce],       p_b2[co]);
    }
    // w_w1 rows bf16-packed: W1pk[p][h] = {w_w1[ce][h], w_w1[co][h]}
    u32 W1pk[4][8];
#pragma unroll
    for (int p = 0; p < 4; p++) {
        int ce = 16 * p + l8, co = ce + 8;
        float4 e0 = *(const float4*)&w_w1[ce * 8];
        float4 e1 = *(const float4*)&w_w1[ce * 8 + 4];
        float4 o0 = *(const float4*)&w_w1[co * 8];
        float4 o1 = *(const float4*)&w_w1[co * 8 + 4];
        W1pk[p][0] = pack2f(e0.x, o0.x); W1pk[p][1] = pack2f(e0.y, o0.y);
        W1pk[p][2] = pack2f(e0.z, o0.z); W1pk[p][3] = pack2f(e0.w, o0.w);
        W1pk[p][4] = pack2f(e1.x, o1.x); W1pk[p][5] = pack2f(e1.y, o1.y);
        W1pk[p][6] = pack2f(e1.z, o1.z); W1pk[p][7] = pack2f(e1.w, o1.w);
    }
    // w_w2 column l8, bf16-packed in h-pairs
    u32 ww2pk[4];
#pragma unroll
    for (int i = 0; i < 4; i++)
        ww2pk[i] = pack2f(w_w2[(2 * i) * 8 + l8], w_w2[(2 * i + 1) * 8 + l8]);
    const float wb2l = w_b2[l8];

    // bn1 scale + offset with q folded: w = relu((k+pj)*s2 + qh2)
    f32x2 s2[4], qh2[4];
    {
        uint4 qr = *(const uint4*)&qt[(size_t)n * 64 + l8 * 8];
        const u32* qw = (const u32*)&qr;
#pragma unroll
        for (int p = 0; p < 4; p++) {
            int ce = 16 * p + l8, co = ce + 8;
            float se = w_bn1_g[ce] * rsqrtf(w_bn1_v[ce] + EPS);
            float so = w_bn1_g[co] * rsqrtf(w_bn1_v[co] + EPS);
            float he = w_bn1_b[ce] - w_bn1_m[ce] * se;
            float ho = w_bn1_b[co] - w_bn1_m[co] * so;
            f32x2 q2 = unpk2(qw[p]);
            s2[p]  = mk2(se, so);
            qh2[p] = mk2(he - q2[0] * se, ho - q2[1] * so);
        }
    }

    const float px = point[n * 3], py = point[n * 3 + 1], pz = point[n * 3 + 2];
    f32x2 acc2[4];
#pragma unroll
    for (int p = 0; p < 4; p++) acc2[p] = mk2(0.f, 0.f);

    // ---- pipelined neighbor loop: idx 2-deep, kv/point 1-deep ----
    const int ib = n * 16;
    int j_nxt = idx[ib];                        // neighbor 0 index
    {   // issue gathers for neighbor 0 (consumed in iteration 0)
    }
    const u16* kp0 = kvt + (size_t)j_nxt * 128 + l8 * 8;
    uint4 kr = *(const uint4*)kp0;
    uint4 vr = *(const uint4*)(kp0 + 64);
    float2 jxy = *(const float2*)&point[j_nxt * 3];
    float  jz  = point[j_nxt * 3 + 2];
    j_nxt = idx[ib + 1];                        // neighbor 1 index (2-deep)

#pragma unroll 4
    for (int kk = 0; kk < 16; kk++) {
        // prefetch: idx for kk+2, gathers for kk+1 (j_nxt)
        int i2 = kk + 2;
        int j_n2 = idx[ib + (i2 < 16 ? i2 : 15)];
        const u16* kpn = kvt + (size_t)j_nxt * 128 + l8 * 8;
        uint4 krn = *(const uint4*)kpn;
        uint4 vrn = *(const uint4*)(kpn + 64);
        float2 jxyn = *(const float2*)&point[j_nxt * 3];
        float  jzn  = point[j_nxt * 3 + 2];

        // linear_p stage 1 (3->3, BN, ReLU) — pre-scaled weights
        float dx = jxy.x - px, dy = jxy.y - py, dz = jz - pz;
        float t0 = fmaxf(0.f, fmaf(dz, pw1s[6], fmaf(dy, pw1s[3], fmaf(dx, pw1s[0], pbh2[0]))));
        float t1 = fmaxf(0.f, fmaf(dz, pw1s[7], fmaf(dy, pw1s[4], fmaf(dx, pw1s[1], pbh2[1]))));
        float t2 = fmaxf(0.f, fmaf(dz, pw1s[8], fmaf(dy, pw1s[5], fmaf(dx, pw1s[2], pbh2[2]))));
        f32x2 tp0 = bc2(t0), tp1 = bc2(t1), tp2 = bc2(t2);

        const u32* kw = (const u32*)&kr;
        float partial[8];
#pragma unroll
        for (int h = 0; h < 8; h++) partial[h] = 0.f;
        f32x2 pjs[4];

#pragma unroll
        for (int p = 0; p < 4; p++) {
            f32x2 pj = PB[p] + tp0 * P0[p] + tp1 * P1[p] + tp2 * P2[p];
            pjs[p] = pj;
            f32x2 kf = unpk2(kw[p]);
            f32x2 w2 = (kf + pj) * s2[p] + qh2[p];
            w2[0] = fmaxf(w2[0], 0.f);
            w2[1] = fmaxf(w2[1], 0.f);
            u32 wpk = cvtpk(w2[0], w2[1]);       // {even, odd} channel pair
#pragma unroll
            for (int h = 0; h < 8; h++) dot2bf(partial[h], wpk, W1pk[p][h]);
        }
        // 64 -> 8 reduce across the 8-lane group (DPP)
#pragma unroll
        for (int h = 0; h < 8; h++) partial[h] = gsum8(partial[h]);

        // relu(bn2(.)) @ w_w2 -> this lane's softmax logit
        float wb[8];
#pragma unroll
        for (int h = 0; h < 8; h++) wb[h] = fmaxf(0.f, fmaf(partial[h], b2s[h], b2hh[h]));
        float y = wb2l;
#pragma unroll
        for (int i = 0; i < 4; i++) dot2bf(y, cvtpk(wb[2 * i], wb[2 * i + 1]), ww2pk[i]);

        // softmax over the 8 lanes of the group
        float mx = gmax8(y);
        float e  = __expf(y - mx);
        float ssum = gsum8(e);
        float sm = e * __builtin_amdgcn_rcpf(ssum);
        f32x2 sm2 = bc2(sm);

        const u32* vw = (const u32*)&vr;
#pragma unroll
        for (int p = 0; p < 4; p++) {
            f32x2 vp = unpk2(vw[p]) + pjs[p];
            acc2[p] += sm2 * vp;
        }

        kr = krn; vr = vrn; jxy = jxyn; jz = jzn; j_nxt = j_n2;
    }

#pragma unroll
    for (int p = 0; p < 4; p++) {
        out[(size_t)n * 64 + 16 * p + l8]     = acc2[p][0];
        out[(size_t)n * 64 + 16 * p + 8 + l8] = acc2[p][1];
    }
}

extern "C" void kernel_launch(void* const* d_in, const int* in_sizes, int n_in,
                              void* d_out, int out_size, void* d_ws, size_t ws_size,
                              hipStream_t stream)
{
    const float* point   = (const float*)d_in[0];
    const float* feat    = (const float*)d_in[1];
    const int*   idx     = (const int*)d_in[2];
    const float* Wq      = (const float*)d_in[3];
    const float* bq      = (const float*)d_in[4];
    const float* Wk      = (const float*)d_in[5];
    const float* bk      = (const float*)d_in[6];
    const float* Wv      = (const float*)d_in[7];
    const float* bv      = (const float*)d_in[8];
    const float* p_w1    = (const float*)d_in[9];
    const float* p_b1    = (const float*)d_in[10];
    const float* p_bn_g  = (const float*)d_in[11];
    const float* p_bn_b  = (const float*)d_in[12];
    const float* p_bn_m  = (const float*)d_in[13];
    const float* p_bn_v  = (const float*)d_in[14];
    const float* p_w2    = (const float*)d_in[15];
    const float* p_b2    = (const float*)d_in[16];
    const float* w_bn1_g = (const float*)d_in[17];
    const float* w_bn1_b = (const float*)d_in[18];
    const float* w_bn1_m = (const float*)d_in[19];
    const float* w_bn1_v = (const float*)d_in[20];
    const float* w_w1    = (const float*)d_in[21];
    const float* w_b1    = (const float*)d_in[22];
    const float* w_bn2_g = (const float*)d_in[23];
    const float* w_bn2_b = (const float*)d_in[24];
    const float* w_bn2_m = (const float*)d_in[25];
    const float* w_bn2_v = (const float*)d_in[26];
    const float* w_w2    = (const float*)d_in[27];
    const float* w_b2    = (const float*)d_in[28];
    float* out = (float*)d_out;

    const int N = in_sizes[0] / 3;   // 65536

    u16* kvt = (u16*)d_ws;                       // N*128 bf16
    u16* qt  = (u16*)d_ws + (size_t)N * 128;     // N*64 bf16

    qkv_kernel<<<N / 128, 256, 0, stream>>>(feat, Wq, bq, Wk, bk, Wv, bv, qt, kvt);
    attn_kernel<<<N / 32, 256, 0, stream>>>(point, idx, qt, kvt,
                                            p_w1, p_b1, p_bn_g, p_bn_b, p_bn_m, p_bn_v, p_w2, p_b2,
                                            w_bn1_g, w_bn1_b, w_bn1_m, w_bn1_v, w_w1, w_b1,
                                            w_bn2_g, w_bn2_b, w_bn2_m, w_bn2_v, w_w2, w_b2,
                                            out);
}

// Round 10
// 86.318 us; speedup vs baseline: 5.0174x; 1.1113x over previous
//
#include <hip/hip_runtime.h>

typedef unsigned short u16;
typedef unsigned int   u32;
typedef float f32x2 __attribute__((ext_vector_type(2)));

// ---- bf16 helpers ----
__device__ __forceinline__ u16 f2b(float f) {
    u32 u = __float_as_uint(f);
    return (u16)((u + 0x7fffu + ((u >> 16) & 1u)) >> 16);
}
__device__ __forceinline__ u32 pack2f(float a, float b) {
    return (u32)f2b(a) | ((u32)f2b(b) << 16);
}
__device__ __forceinline__ f32x2 unpk2(u32 w) {
    f32x2 r;
    r[0] = __uint_as_float(w << 16);
    r[1] = __uint_as_float(w & 0xffff0000u);
    return r;
}
__device__ __forceinline__ int permc(int c) { return ((c & 7) << 3) | (c >> 3); }
__device__ __forceinline__ f32x2 bc2(float x) { f32x2 r; r[0] = x; r[1] = x; return r; }
__device__ __forceinline__ f32x2 mk2(float a, float b) { f32x2 r; r[0] = a; r[1] = b; return r; }

// packed bf16 dot: c += a.lo*b.lo + a.hi*b.hi
__device__ __forceinline__ void dot2bf(float& c, u32 a, u32 b) {
    asm("v_dot2_f32_bf16 %0, %1, %2, %0" : "+v"(c) : "v"(a), "v"(b));
}
__device__ __forceinline__ u32 cvtpk(float lo, float hi) {
    u32 r;
    asm("v_cvt_pk_bf16_f32 %0, %1, %2" : "=v"(r) : "v"(lo), "v"(hi));
    return r;
}

// ---- DPP cross-lane via BUILTIN (compiler inserts VALU->DPP wait states) ----
template<int CTRL>
__device__ __forceinline__ float dppf(float x) {
    return __int_as_float(__builtin_amdgcn_update_dpp(0, __float_as_int(x), CTRL, 0xf, 0xf, true));
}
__device__ __forceinline__ float gsum8(float x) {
    x += dppf<0xB1>(x);    // quad_perm [1,0,3,2]  (xor 1)
    x += dppf<0x4E>(x);    // quad_perm [2,3,0,1]  (xor 2)
    x += dppf<0x141>(x);   // row_half_mirror      (cross-quad within 8)
    return x;
}
__device__ __forceinline__ float gmax8(float x) {
    x = fmaxf(x, dppf<0xB1>(x));
    x = fmaxf(x, dppf<0x4E>(x));
    x = fmaxf(x, dppf<0x141>(x));
    return x;
}

// ======= Kernel 1: q/k/v projections, dot2bf inner loop (R7/R9 version) ======
// Validated innocent by R7-vs-R8 and R8-vs-R9 bit-identical absmax.
__global__ __launch_bounds__(256) void qkv_kernel(
    const float* __restrict__ feat,
    const float* __restrict__ Wq, const float* __restrict__ bq,
    const float* __restrict__ Wk, const float* __restrict__ bk,
    const float* __restrict__ Wv, const float* __restrict__ bv,
    u16* __restrict__ qt, u16* __restrict__ kvt)
{
    __shared__ u32 wpk[3][32][64];    // wpk[m][ip][slot] = bf16pair(W[2ip][ch], W[2ip+1][ch]), slot=permc(ch)
    __shared__ u32 fpk[32][132];      // fpk[ip][r] = bf16pair(feat[r][2ip], feat[r][2ip+1]), r<128
    const int t = threadIdx.x;
    const int rowbase = blockIdx.x * 128;

    {
        const float* Ws[3] = {Wq, Wk, Wv};
#pragma unroll
        for (int mm = 0; mm < 3; mm++) {
            for (int e = t; e < 512; e += 256) {
                int ip = e >> 4, c4 = (e & 15) * 4;
                float4 wa = *(const float4*)&Ws[mm][(2 * ip) * 64 + c4];
                float4 wb = *(const float4*)&Ws[mm][(2 * ip + 1) * 64 + c4];
                wpk[mm][ip][permc(c4 + 0)] = pack2f(wa.x, wb.x);
                wpk[mm][ip][permc(c4 + 1)] = pack2f(wa.y, wb.y);
                wpk[mm][ip][permc(c4 + 2)] = pack2f(wa.z, wb.z);
                wpk[mm][ip][permc(c4 + 3)] = pack2f(wa.w, wb.w);
            }
        }
    }
    for (int e = t; e < 2048; e += 256) {
        int r = e >> 4, ip2 = (e & 15) * 2;
        float4 v = *(const float4*)&feat[(size_t)(rowbase + r) * 64 + ip2 * 2];
        fpk[ip2][r]     = pack2f(v.x, v.y);
        fpk[ip2 + 1][r] = pack2f(v.z, v.w);
    }
    __syncthreads();

    const int rg = t >> 3;        // rows 4rg..4rg+3
    const int q8 = t & 7;
    const int c0 = q8 * 8;        // slot c0+x holds original channel x*8+q8

    float acc[3][4][8];
    {
        const float* Bs[3] = {bq, bk, bv};
#pragma unroll
        for (int m = 0; m < 3; m++)
#pragma unroll
            for (int x = 0; x < 8; x++) {
                float b = Bs[m][x * 8 + q8];
#pragma unroll
                for (int r = 0; r < 4; r++) acc[m][r][x] = b;
            }
    }

#pragma unroll 2
    for (int ip = 0; ip < 32; ip++) {
        uint4 f4 = *(const uint4*)&fpk[ip][rg * 4];
        u32 fr[4] = {f4.x, f4.y, f4.z, f4.w};
#pragma unroll
        for (int m = 0; m < 3; m++) {
            uint4 wv0 = *(const uint4*)&wpk[m][ip][c0];
            uint4 wv1 = *(const uint4*)&wpk[m][ip][c0 + 4];
            u32 wc[8] = {wv0.x, wv0.y, wv0.z, wv0.w, wv1.x, wv1.y, wv1.z, wv1.w};
#pragma unroll
            for (int r = 0; r < 4; r++)
#pragma unroll
                for (int x = 0; x < 8; x++)
                    dot2bf(acc[m][r][x], fr[r], wc[x]);
        }
    }

#pragma unroll
    for (int r = 0; r < 4; r++) {
        int row = rowbase + rg * 4 + r;
        uint4 oq, ok, ov;
        oq.x = cvtpk(acc[0][r][0], acc[0][r][1]); oq.y = cvtpk(acc[0][r][2], acc[0][r][3]);
        oq.z = cvtpk(acc[0][r][4], acc[0][r][5]); oq.w = cvtpk(acc[0][r][6], acc[0][r][7]);
        ok.x = cvtpk(acc[1][r][0], acc[1][r][1]); ok.y = cvtpk(acc[1][r][2], acc[1][r][3]);
        ok.z = cvtpk(acc[1][r][4], acc[1][r][5]); ok.w = cvtpk(acc[1][r][6], acc[1][r][7]);
        ov.x = cvtpk(acc[2][r][0], acc[2][r][1]); ov.y = cvtpk(acc[2][r][2], acc[2][r][3]);
        ov.z = cvtpk(acc[2][r][4], acc[2][r][5]); ov.w = cvtpk(acc[2][r][6], acc[2][r][7]);
        *(uint4*)&qt [(size_t)row * 64 + c0]       = oq;
        *(uint4*)&kvt[(size_t)row * 128 + c0]      = ok;
        *(uint4*)&kvt[(size_t)row * 128 + 64 + c0] = ov;
    }
}

// ===== Kernel 2: fused gather + attention — R4 datapath, max-sub RESTORED =====
// (max-subtraction is load-bearing: R4/R1 pass with it, R6-R9 all fail 0.1328
//  without it, invariant to every other change. Do not remove again.)
__global__ __launch_bounds__(256) void attn_kernel(
    const float* __restrict__ point,
    const int*   __restrict__ idx,
    const u16*   __restrict__ qt,
    const u16*   __restrict__ kvt,
    const float* __restrict__ p_w1,   const float* __restrict__ p_b1,
    const float* __restrict__ p_bn_g, const float* __restrict__ p_bn_b,
    const float* __restrict__ p_bn_m, const float* __restrict__ p_bn_v,
    const float* __restrict__ p_w2,   const float* __restrict__ p_b2,
    const float* __restrict__ w_bn1_g, const float* __restrict__ w_bn1_b,
    const float* __restrict__ w_bn1_m, const float* __restrict__ w_bn1_v,
    const float* __restrict__ w_w1,    const float* __restrict__ w_b1,
    const float* __restrict__ w_bn2_g, const float* __restrict__ w_bn2_b,
    const float* __restrict__ w_bn2_m, const float* __restrict__ w_bn2_v,
    const float* __restrict__ w_w2,    const float* __restrict__ w_b2,
    float* __restrict__ out)
{
    const int t  = threadIdx.x;
    const int l8 = t & 7;
    const int n  = blockIdx.x * 32 + (t >> 3);
    const float EPS = 1e-5f;

    // ---- wave-uniform params (SGPR) ----
    float pw1[9];
#pragma unroll
    for (int i = 0; i < 9; i++) pw1[i] = p_w1[i];
    float pb1b[3], pbs[3], pbh[3];
#pragma unroll
    for (int a = 0; a < 3; a++) {
        float s = p_bn_g[a] * rsqrtf(p_bn_v[a] + EPS);
        pb1b[a] = p_b1[a];
        pbs[a]  = s;
        pbh[a]  = p_bn_b[a] - p_bn_m[a] * s;
    }
    float b2s[8], b2hh[8];
#pragma unroll
    for (int h = 0; h < 8; h++) {
        float s = w_bn2_g[h] * rsqrtf(w_bn2_v[h] + EPS);
        b2s[h]  = s;
        b2hh[h] = (w_bn2_b[h] - w_bn2_m[h] * s) + w_b1[h] * s;
    }

    // ---- per-lane register params ----
    f32x2 P0[4], P1[4], P2[4], PB[4];
#pragma unroll
    for (int p = 0; p < 4; p++) {
        int ce = 16 * p + l8, co = ce + 8;
        P0[p] = mk2(p_w2[ce],       p_w2[co]);
        P1[p] = mk2(p_w2[64 + ce],  p_w2[64 + co]);
        P2[p] = mk2(p_w2[128 + ce], p_w2[128 + co]);
        PB[p] = mk2(p_b2[ce],       p_b2[co]);
    }
    u32 W1pk[4][8];
#pragma unroll
    for (int p = 0; p < 4; p++) {
        int ce = 16 * p + l8, co = ce + 8;
        float4 e0 = *(const float4*)&w_w1[ce * 8];
        float4 e1 = *(const float4*)&w_w1[ce * 8 + 4];
        float4 o0 = *(const float4*)&w_w1[co * 8];
        float4 o1 = *(const float4*)&w_w1[co * 8 + 4];
        W1pk[p][0] = pack2f(e0.x, o0.x); W1pk[p][1] = pack2f(e0.y, o0.y);
        W1pk[p][2] = pack2f(e0.z, o0.z); W1pk[p][3] = pack2f(e0.w, o0.w);
        W1pk[p][4] = pack2f(e1.x, o1.x); W1pk[p][5] = pack2f(e1.y, o1.y);
        W1pk[p][6] = pack2f(e1.z, o1.z); W1pk[p][7] = pack2f(e1.w, o1.w);
    }
    u32 ww2pk[4];
#pragma unroll
    for (int i = 0; i < 4; i++)
        ww2pk[i] = pack2f(w_w2[(2 * i) * 8 + l8], w_w2[(2 * i + 1) * 8 + l8]);
    const float wb2l = w_b2[l8];

    // bn1 scale + offset with q folded: w = relu((k+pj)*s2 + qh2)
    f32x2 s2[4], qh2[4];
    {
        uint4 qr = *(const uint4*)&qt[(size_t)n * 64 + l8 * 8];
        const u32* qw = (const u32*)&qr;
#pragma unroll
        for (int p = 0; p < 4; p++) {
            int ce = 16 * p + l8, co = ce + 8;
            float se = w_bn1_g[ce] * rsqrtf(w_bn1_v[ce] + EPS);
            float so = w_bn1_g[co] * rsqrtf(w_bn1_v[co] + EPS);
            float he = w_bn1_b[ce] - w_bn1_m[ce] * se;
            float ho = w_bn1_b[co] - w_bn1_m[co] * so;
            f32x2 q2 = unpk2(qw[p]);
            s2[p]  = mk2(se, so);
            qh2[p] = mk2(he - q2[0] * se, ho - q2[1] * so);
        }
    }

    const float px = point[n * 3], py = point[n * 3 + 1], pz = point[n * 3 + 2];
    f32x2 acc2[4];
#pragma unroll
    for (int p = 0; p < 4; p++) acc2[p] = mk2(0.f, 0.f);

    // ---- pipelined neighbor loop: idx 2-deep, kv/point 1-deep ----
    const int ib = n * 16;
    int j_nxt = idx[ib];
    const u16* kp0 = kvt + (size_t)j_nxt * 128 + l8 * 8;
    uint4 kr = *(const uint4*)kp0;
    uint4 vr = *(const uint4*)(kp0 + 64);
    float2 jxy = *(const float2*)&point[j_nxt * 3];
    float  jz  = point[j_nxt * 3 + 2];
    j_nxt = idx[ib + 1];

#pragma unroll 4
    for (int kk = 0; kk < 16; kk++) {
        int i2 = kk + 2;
        int j_n2 = idx[ib + (i2 < 16 ? i2 : 15)];
        const u16* kpn = kvt + (size_t)j_nxt * 128 + l8 * 8;
        uint4 krn = *(const uint4*)kpn;
        uint4 vrn = *(const uint4*)(kpn + 64);
        float2 jxyn = *(const float2*)&point[j_nxt * 3];
        float  jzn  = point[j_nxt * 3 + 2];

        // linear_p stage 1 (3->3, BN, ReLU)
        float dx = jxy.x - px, dy = jxy.y - py, dz = jz - pz;
        float t0 = fmaxf(0.f, fmaf(fmaf(dz, pw1[6], fmaf(dy, pw1[3], fmaf(dx, pw1[0], pb1b[0]))), pbs[0], pbh[0]));
        float t1 = fmaxf(0.f, fmaf(fmaf(dz, pw1[7], fmaf(dy, pw1[4], fmaf(dx, pw1[1], pb1b[1]))), pbs[1], pbh[1]));
        float t2 = fmaxf(0.f, fmaf(fmaf(dz, pw1[8], fmaf(dy, pw1[5], fmaf(dx, pw1[2], pb1b[2]))), pbs[2], pbh[2]));
        f32x2 tp0 = bc2(t0), tp1 = bc2(t1), tp2 = bc2(t2);

        const u32* kw = (const u32*)&kr;
        float partial[8];
#pragma unroll
        for (int h = 0; h < 8; h++) partial[h] = 0.f;
        f32x2 pjs[4];

#pragma unroll
        for (int p = 0; p < 4; p++) {
            f32x2 pj = PB[p] + tp0 * P0[p] + tp1 * P1[p] + tp2 * P2[p];
            pjs[p] = pj;
            f32x2 kf = unpk2(kw[p]);
            f32x2 w2 = (kf + pj) * s2[p] + qh2[p];
            u32 wpk_ = cvtpk(fmaxf(w2[0], 0.f), fmaxf(w2[1], 0.f));
#pragma unroll
            for (int h = 0; h < 8; h++) dot2bf(partial[h], wpk_, W1pk[p][h]);
        }
        // 64 -> 8 reduce across the 8-lane group
#pragma unroll
        for (int h = 0; h < 8; h++) partial[h] = gsum8(partial[h]);

        // relu(bn2(.)) @ w_w2 -> this lane's softmax logit
        float wb[8];
#pragma unroll
        for (int h = 0; h < 8; h++) wb[h] = fmaxf(0.f, fmaf(partial[h], b2s[h], b2hh[h]));
        float y = wb2l;
#pragma unroll
        for (int i = 0; i < 4; i++) dot2bf(y, cvtpk(wb[2 * i], wb[2 * i + 1]), ww2pk[i]);

        // softmax over the 8 lanes of the group — WITH max-subtraction
        float mx = gmax8(y);
        float e  = __expf(y - mx);
        float ssum = gsum8(e);
        float sm = e * __builtin_amdgcn_rcpf(ssum);
        f32x2 sm2 = bc2(sm);

        const u32* vw = (const u32*)&vr;
#pragma unroll
        for (int p = 0; p < 4; p++) {
            f32x2 vp = unpk2(vw[p]) + pjs[p];
            acc2[p] += sm2 * vp;
        }

        kr = krn; vr = vrn; jxy = jxyn; jz = jzn; j_nxt = j_n2;
    }

#pragma unroll
    for (int p = 0; p < 4; p++) {
        out[(size_t)n * 64 + 16 * p + l8]     = acc2[p][0];
        out[(size_t)n * 64 + 16 * p + 8 + l8] = acc2[p][1];
    }
}

extern "C" void kernel_launch(void* const* d_in, const int* in_sizes, int n_in,
                              void* d_out, int out_size, void* d_ws, size_t ws_size,
                              hipStream_t stream)
{
    const float* point   = (const float*)d_in[0];
    const float* feat    = (const float*)d_in[1];
    const int*   idx     = (const int*)d_in[2];
    const float* Wq      = (const float*)d_in[3];
    const float* bq      = (const float*)d_in[4];
    const float* Wk      = (const float*)d_in[5];
    const float* bk      = (const float*)d_in[6];
    const float* Wv      = (const float*)d_in[7];
    const float* bv      = (const float*)d_in[8];
    const float* p_w1    = (const float*)d_in[9];
    const float* p_b1    = (const float*)d_in[10];
    const float* p_bn_g  = (const float*)d_in[11];
    const float* p_bn_b  = (const float*)d_in[12];
    const float* p_bn_m  = (const float*)d_in[13];
    const float* p_bn_v  = (const float*)d_in[14];
    const float* p_w2    = (const float*)d_in[15];
    const float* p_b2    = (const float*)d_in[16];
    const float* w_bn1_g = (const float*)d_in[17];
    const float* w_bn1_b = (const float*)d_in[18];
    const float* w_bn1_m = (const float*)d_in[19];
    const float* w_bn1_v = (const float*)d_in[20];
    const float* w_w1    = (const float*)d_in[21];
    const float* w_b1    = (const float*)d_in[22];
    const float* w_bn2_g = (const float*)d_in[23];
    const float* w_bn2_b = (const float*)d_in[24];
    const float* w_bn2_m = (const float*)d_in[25];
    const float* w_bn2_v = (const float*)d_in[26];
    const float* w_w2    = (const float*)d_in[27];
    const float* w_b2    = (const float*)d_in[28];
    float* out = (float*)d_out;

    const int N = in_sizes[0] / 3;   // 65536

    u16* kvt = (u16*)d_ws;                       // N*128 bf16
    u16* qt  = (u16*)d_ws + (size_t)N * 128;     // N*64 bf16

    qkv_kernel<<<N / 128, 256, 0, stream>>>(feat, Wq, bq, Wk, bk, Wv, bv, qt, kvt);
    attn_kernel<<<N / 32, 256, 0, stream>>>(point, idx, qt, kvt,
                                            p_w1, p_b1, p_bn_g, p_bn_b, p_bn_m, p_bn_v, p_w2, p_b2,
                                            w_bn1_g, w_bn1_b, w_bn1_m, w_bn1_v, w_w1, w_b1,
                                            w_bn2_g, w_bn2_b, w_bn2_m, w_bn2_v, w_w2, w_b2,
                                            out);
}

// Round 11
// 83.344 us; speedup vs baseline: 5.1964x; 1.0357x over previous
//
#include <hip/hip_runtime.h>

typedef unsigned short u16;
typedef unsigned int   u32;
typedef float f32x2 __attribute__((ext_vector_type(2)));

// ---- bf16 helpers ----
__device__ __forceinline__ u16 f2b(float f) {
    u32 u = __float_as_uint(f);
    return (u16)((u + 0x7fffu + ((u >> 16) & 1u)) >> 16);
}
__device__ __forceinline__ u32 pack2f(float a, float b) {
    return (u32)f2b(a) | ((u32)f2b(b) << 16);
}
__device__ __forceinline__ f32x2 unpk2(u32 w) {
    f32x2 r;
    r[0] = __uint_as_float(w << 16);
    r[1] = __uint_as_float(w & 0xffff0000u);
    return r;
}
__device__ __forceinline__ int permc(int c) { return ((c & 7) << 3) | (c >> 3); }
__device__ __forceinline__ f32x2 bc2(float x) { f32x2 r; r[0] = x; r[1] = x; return r; }
__device__ __forceinline__ f32x2 mk2(float a, float b) { f32x2 r; r[0] = a; r[1] = b; return r; }

// packed bf16 dot: c += a.lo*b.lo + a.hi*b.hi
__device__ __forceinline__ void dot2bf(float& c, u32 a, u32 b) {
    asm("v_dot2_f32_bf16 %0, %1, %2, %0" : "+v"(c) : "v"(a), "v"(b));
}
__device__ __forceinline__ u32 cvtpk(float lo, float hi) {
    u32 r;
    asm("v_cvt_pk_bf16_f32 %0, %1, %2" : "=v"(r) : "v"(lo), "v"(hi));
    return r;
}

// ---- DPP cross-lane via BUILTIN (compiler inserts VALU->DPP wait states) ----
// controls: 0xB1 = quad_perm[1,0,3,2] (xor1); 0x4E = quad_perm[2,3,0,1] (xor2);
//           0x141 = row_half_mirror (lane -> lane^7 within aligned 8)
template<int CTRL>
__device__ __forceinline__ float dppf(float x) {
    return __int_as_float(__builtin_amdgcn_update_dpp(0, __float_as_int(x), CTRL, 0xf, 0xf, true));
}
__device__ __forceinline__ float gsum8(float x) {
    x += dppf<0xB1>(x);
    x += dppf<0x4E>(x);
    x += dppf<0x141>(x);
    return x;
}
__device__ __forceinline__ float gmax8(float x) {
    x = fmaxf(x, dppf<0xB1>(x));
    x = fmaxf(x, dppf<0x4E>(x));
    x = fmaxf(x, dppf<0x141>(x));
    return x;
}
// slot->h map for the {xor1, xor2, mirror(=xor7)} butterfly: h = phi(r) ^ lane
__device__ __forceinline__ int phi8(int r) { return (r < 4) ? r : (r ^ 3); }

// ======= Kernel 1: q/k/v projections, dot2bf inner loop (R10, proven) ========
__global__ __launch_bounds__(256) void qkv_kernel(
    const float* __restrict__ feat,
    const float* __restrict__ Wq, const float* __restrict__ bq,
    const float* __restrict__ Wk, const float* __restrict__ bk,
    const float* __restrict__ Wv, const float* __restrict__ bv,
    u16* __restrict__ qt, u16* __restrict__ kvt)
{
    __shared__ u32 wpk[3][32][64];
    __shared__ u32 fpk[32][132];
    const int t = threadIdx.x;
    const int rowbase = blockIdx.x * 128;

    {
        const float* Ws[3] = {Wq, Wk, Wv};
#pragma unroll
        for (int mm = 0; mm < 3; mm++) {
            for (int e = t; e < 512; e += 256) {
                int ip = e >> 4, c4 = (e & 15) * 4;
                float4 wa = *(const float4*)&Ws[mm][(2 * ip) * 64 + c4];
                float4 wb = *(const float4*)&Ws[mm][(2 * ip + 1) * 64 + c4];
                wpk[mm][ip][permc(c4 + 0)] = pack2f(wa.x, wb.x);
                wpk[mm][ip][permc(c4 + 1)] = pack2f(wa.y, wb.y);
                wpk[mm][ip][permc(c4 + 2)] = pack2f(wa.z, wb.z);
                wpk[mm][ip][permc(c4 + 3)] = pack2f(wa.w, wb.w);
            }
        }
    }
    for (int e = t; e < 2048; e += 256) {
        int r = e >> 4, ip2 = (e & 15) * 2;
        float4 v = *(const float4*)&feat[(size_t)(rowbase + r) * 64 + ip2 * 2];
        fpk[ip2][r]     = pack2f(v.x, v.y);
        fpk[ip2 + 1][r] = pack2f(v.z, v.w);
    }
    __syncthreads();

    const int rg = t >> 3;
    const int q8 = t & 7;
    const int c0 = q8 * 8;

    float acc[3][4][8];
    {
        const float* Bs[3] = {bq, bk, bv};
#pragma unroll
        for (int m = 0; m < 3; m++)
#pragma unroll
            for (int x = 0; x < 8; x++) {
                float b = Bs[m][x * 8 + q8];
#pragma unroll
                for (int r = 0; r < 4; r++) acc[m][r][x] = b;
            }
    }

#pragma unroll 2
    for (int ip = 0; ip < 32; ip++) {
        uint4 f4 = *(const uint4*)&fpk[ip][rg * 4];
        u32 fr[4] = {f4.x, f4.y, f4.z, f4.w};
#pragma unroll
        for (int m = 0; m < 3; m++) {
            uint4 wv0 = *(const uint4*)&wpk[m][ip][c0];
            uint4 wv1 = *(const uint4*)&wpk[m][ip][c0 + 4];
            u32 wc[8] = {wv0.x, wv0.y, wv0.z, wv0.w, wv1.x, wv1.y, wv1.z, wv1.w};
#pragma unroll
            for (int r = 0; r < 4; r++)
#pragma unroll
                for (int x = 0; x < 8; x++)
                    dot2bf(acc[m][r][x], fr[r], wc[x]);
        }
    }

#pragma unroll
    for (int r = 0; r < 4; r++) {
        int row = rowbase + rg * 4 + r;
        uint4 oq, ok, ov;
        oq.x = cvtpk(acc[0][r][0], acc[0][r][1]); oq.y = cvtpk(acc[0][r][2], acc[0][r][3]);
        oq.z = cvtpk(acc[0][r][4], acc[0][r][5]); oq.w = cvtpk(acc[0][r][6], acc[0][r][7]);
        ok.x = cvtpk(acc[1][r][0], acc[1][r][1]); ok.y = cvtpk(acc[1][r][2], acc[1][r][3]);
        ok.z = cvtpk(acc[1][r][4], acc[1][r][5]); ok.w = cvtpk(acc[1][r][6], acc[1][r][7]);
        ov.x = cvtpk(acc[2][r][0], acc[2][r][1]); ov.y = cvtpk(acc[2][r][2], acc[2][r][3]);
        ov.z = cvtpk(acc[2][r][4], acc[2][r][5]); ov.w = cvtpk(acc[2][r][6], acc[2][r][7]);
        *(uint4*)&qt [(size_t)row * 64 + c0]       = oq;
        *(uint4*)&kvt[(size_t)row * 128 + c0]      = ok;
        *(uint4*)&kvt[(size_t)row * 128 + 64 + c0] = ov;
    }
}

// ===== Kernel 2: fused gather + attention =====
// R10 datapath (max-sub KEPT — load-bearing, R6-R9 evidence) with two changes:
//  (a) 64->8 via reduce-scatter + scalar bn2 + all-gather (phi-mapped slots),
//      replacing the 8-value butterfly all-reduce: 31 instr vs 72.
//  (b) idx row preloaded as 4x int4 (contiguous 64B), removing per-iter idx load.
__global__ __launch_bounds__(256) void attn_kernel(
    const float* __restrict__ point,
    const int*   __restrict__ idx,
    const u16*   __restrict__ qt,
    const u16*   __restrict__ kvt,
    const float* __restrict__ p_w1,   const float* __restrict__ p_b1,
    const float* __restrict__ p_bn_g, const float* __restrict__ p_bn_b,
    const float* __restrict__ p_bn_m, const float* __restrict__ p_bn_v,
    const float* __restrict__ p_w2,   const float* __restrict__ p_b2,
    const float* __restrict__ w_bn1_g, const float* __restrict__ w_bn1_b,
    const float* __restrict__ w_bn1_m, const float* __restrict__ w_bn1_v,
    const float* __restrict__ w_w1,    const float* __restrict__ w_b1,
    const float* __restrict__ w_bn2_g, const float* __restrict__ w_bn2_b,
    const float* __restrict__ w_bn2_m, const float* __restrict__ w_bn2_v,
    const float* __restrict__ w_w2,    const float* __restrict__ w_b2,
    float* __restrict__ out)
{
    const int t  = threadIdx.x;
    const int l8 = t & 7;
    const int n  = blockIdx.x * 32 + (t >> 3);
    const float EPS = 1e-5f;

    // ---- wave-uniform params (SGPR) ----
    float pw1[9];
#pragma unroll
    for (int i = 0; i < 9; i++) pw1[i] = p_w1[i];
    float pb1b[3], pbs[3], pbh[3];
#pragma unroll
    for (int a = 0; a < 3; a++) {
        float s = p_bn_g[a] * rsqrtf(p_bn_v[a] + EPS);
        pb1b[a] = p_b1[a];
        pbs[a]  = s;
        pbh[a]  = p_bn_b[a] - p_bn_m[a] * s;
    }

    // ---- per-lane register params ----
    f32x2 P0[4], P1[4], P2[4], PB[4];
#pragma unroll
    for (int p = 0; p < 4; p++) {
        int ce = 16 * p + l8, co = ce + 8;
        P0[p] = mk2(p_w2[ce],       p_w2[co]);
        P1[p] = mk2(p_w2[64 + ce],  p_w2[64 + co]);
        P2[p] = mk2(p_w2[128 + ce], p_w2[128 + co]);
        PB[p] = mk2(p_b2[ce],       p_b2[co]);
    }
    // w_w1 columns, phi-permuted per lane: W1pk[p][r] = col h = phi(r)^l8
    u32 W1pk[4][8];
#pragma unroll
    for (int p = 0; p < 4; p++) {
        int ce = 16 * p + l8, co = ce + 8;
#pragma unroll
        for (int r = 0; r < 8; r++) {
            int hh = phi8(r) ^ l8;
            W1pk[p][r] = pack2f(w_w1[ce * 8 + hh], w_w1[co * 8 + hh]);
        }
    }
    // bn2 for this lane's h = l8 only (scalar)
    float b2s_l, b2hh_l;
    {
        float s = w_bn2_g[l8] * rsqrtf(w_bn2_v[l8] + EPS);
        b2s_l  = s;
        b2hh_l = (w_bn2_b[l8] - w_bn2_m[l8] * s) + w_b1[l8] * s;
    }
    // w_w2 column l8, ordered by all-gather slot j: h = phi(j)^l8
    u32 ww2xpk[4];
#pragma unroll
    for (int i = 0; i < 4; i++) {
        int h0 = phi8(2 * i)     ^ l8;
        int h1 = phi8(2 * i + 1) ^ l8;
        ww2xpk[i] = pack2f(w_w2[h0 * 8 + l8], w_w2[h1 * 8 + l8]);
    }
    const float wb2l = w_b2[l8];

    // bn1 scale + offset with q folded: w = relu((k+pj)*s2 + qh2)
    f32x2 s2[4], qh2[4];
    {
        uint4 qr = *(const uint4*)&qt[(size_t)n * 64 + l8 * 8];
        const u32* qw = (const u32*)&qr;
#pragma unroll
        for (int p = 0; p < 4; p++) {
            int ce = 16 * p + l8, co = ce + 8;
            float se = w_bn1_g[ce] * rsqrtf(w_bn1_v[ce] + EPS);
            float so = w_bn1_g[co] * rsqrtf(w_bn1_v[co] + EPS);
            float he = w_bn1_b[ce] - w_bn1_m[ce] * se;
            float ho = w_bn1_b[co] - w_bn1_m[co] * so;
            f32x2 q2 = unpk2(qw[p]);
            s2[p]  = mk2(se, so);
            qh2[p] = mk2(he - q2[0] * se, ho - q2[1] * so);
        }
    }

    const float px = point[n * 3], py = point[n * 3 + 1], pz = point[n * 3 + 2];
    f32x2 acc2[4];
#pragma unroll
    for (int p = 0; p < 4; p++) acc2[p] = mk2(0.f, 0.f);

    // ---- neighbor loop: idx preloaded as int4; kv/point prefetch 1-deep ----
    uint4 kr, vr;
    float2 jxy;
    float  jz;

    auto proc = [&](int jn) {
        const u16* kpn = kvt + (size_t)jn * 128 + l8 * 8;
        uint4 krn = *(const uint4*)kpn;
        uint4 vrn = *(const uint4*)(kpn + 64);
        float2 jxyn = *(const float2*)&point[jn * 3];
        float  jzn  = point[jn * 3 + 2];

        // linear_p stage 1 (3->3, BN, ReLU)
        float dx = jxy.x - px, dy = jxy.y - py, dz = jz - pz;
        float t0 = fmaxf(0.f, fmaf(fmaf(dz, pw1[6], fmaf(dy, pw1[3], fmaf(dx, pw1[0], pb1b[0]))), pbs[0], pbh[0]));
        float t1 = fmaxf(0.f, fmaf(fmaf(dz, pw1[7], fmaf(dy, pw1[4], fmaf(dx, pw1[1], pb1b[1]))), pbs[1], pbh[1]));
        float t2 = fmaxf(0.f, fmaf(fmaf(dz, pw1[8], fmaf(dy, pw1[5], fmaf(dx, pw1[2], pb1b[2]))), pbs[2], pbh[2]));
        f32x2 tp0 = bc2(t0), tp1 = bc2(t1), tp2 = bc2(t2);

        const u32* kw = (const u32*)&kr;
        float part[8];
#pragma unroll
        for (int h = 0; h < 8; h++) part[h] = 0.f;
        f32x2 pjs[4];

#pragma unroll
        for (int p = 0; p < 4; p++) {
            f32x2 pj = PB[p] + tp0 * P0[p] + tp1 * P1[p] + tp2 * P2[p];
            pjs[p] = pj;
            f32x2 kf = unpk2(kw[p]);
            f32x2 w2 = (kf + pj) * s2[p] + qh2[p];
            u32 wpk_ = cvtpk(fmaxf(w2[0], 0.f), fmaxf(w2[1], 0.f));
#pragma unroll
            for (int r = 0; r < 8; r++) dot2bf(part[r], wpk_, W1pk[p][r]);
        }
        // reduce-scatter (slots: h = phi(r)^lane; stages xor1, xor2, mirror)
        part[0] += dppf<0xB1>(part[1]);
        part[2] += dppf<0xB1>(part[3]);
        part[4] += dppf<0xB1>(part[5]);
        part[6] += dppf<0xB1>(part[7]);
        part[0] += dppf<0x4E>(part[2]);
        part[4] += dppf<0x4E>(part[6]);
        part[0] += dppf<0x141>(part[4]);
        // scalar bn2 for this lane's h = l8
        float wbl = fmaxf(0.f, fmaf(part[0], b2s_l, b2hh_l));
        // all-gather wb across the 8 lanes (slot j holds wb of h = phi(j)^l8)
        float u1 = dppf<0xB1>(wbl);
        float u2 = dppf<0x4E>(wbl);
        float u3 = dppf<0x4E>(u1);
        float u4 = dppf<0x141>(wbl);
        float u5 = dppf<0x141>(u1);
        float u6 = dppf<0x141>(u2);
        float u7 = dppf<0x141>(u3);
        float y = wb2l;
        dot2bf(y, cvtpk(wbl, u1), ww2xpk[0]);
        dot2bf(y, cvtpk(u2, u3), ww2xpk[1]);
        dot2bf(y, cvtpk(u4, u5), ww2xpk[2]);
        dot2bf(y, cvtpk(u6, u7), ww2xpk[3]);

        // softmax over the 8 lanes — WITH max-subtraction (load-bearing)
        float mx = gmax8(y);
        float e  = __expf(y - mx);
        float ssum = gsum8(e);
        float sm = e * __builtin_amdgcn_rcpf(ssum);
        f32x2 sm2 = bc2(sm);

        const u32* vw = (const u32*)&vr;
#pragma unroll
        for (int p = 0; p < 4; p++) {
            f32x2 vp = unpk2(vw[p]) + pjs[p];
            acc2[p] += sm2 * vp;
        }

        kr = krn; vr = vrn; jxy = jxyn; jz = jzn;
    };

    const int4* idxq = (const int4*)(idx + n * 16);   // 64B-aligned row
    int4 I = idxq[0];
    {
        const u16* kp0 = kvt + (size_t)I.x * 128 + l8 * 8;
        kr  = *(const uint4*)kp0;
        vr  = *(const uint4*)(kp0 + 64);
        jxy = *(const float2*)&point[I.x * 3];
        jz  = point[I.x * 3 + 2];
    }
#pragma unroll
    for (int kg = 0; kg < 4; kg++) {
        int4 In = (kg < 3) ? idxq[kg + 1] : I;   // static offset under unroll
        proc(I.y);
        proc(I.z);
        proc(I.w);
        proc(In.x);   // last group: re-prefetch of a processed nbr, harmless
        I = In;
    }

#pragma unroll
    for (int p = 0; p < 4; p++) {
        out[(size_t)n * 64 + 16 * p + l8]     = acc2[p][0];
        out[(size_t)n * 64 + 16 * p + 8 + l8] = acc2[p][1];
    }
}

extern "C" void kernel_launch(void* const* d_in, const int* in_sizes, int n_in,
                              void* d_out, int out_size, void* d_ws, size_t ws_size,
                              hipStream_t stream)
{
    const float* point   = (const float*)d_in[0];
    const float* feat    = (const float*)d_in[1];
    const int*   idx     = (const int*)d_in[2];
    const float* Wq      = (const float*)d_in[3];
    const float* bq      = (const float*)d_in[4];
    const float* Wk      = (const float*)d_in[5];
    const float* bk      = (const float*)d_in[6];
    const float* Wv      = (const float*)d_in[7];
    const float* bv      = (const float*)d_in[8];
    const float* p_w1    = (const float*)d_in[9];
    const float* p_b1    = (const float*)d_in[10];
    const float* p_bn_g  = (const float*)d_in[11];
    const float* p_bn_b  = (const float*)d_in[12];
    const float* p_bn_m  = (const float*)d_in[13];
    const float* p_bn_v  = (const float*)d_in[14];
    const float* p_w2    = (const float*)d_in[15];
    const float* p_b2    = (const float*)d_in[16];
    const float* w_bn1_g = (const float*)d_in[17];
    const float* w_bn1_b = (const float*)d_in[18];
    const float* w_bn1_m = (const float*)d_in[19];
    const float* w_bn1_v = (const float*)d_in[20];
    const float* w_w1    = (const float*)d_in[21];
    const float* w_b1    = (const float*)d_in[22];
    const float* w_bn2_g = (const float*)d_in[23];
    const float* w_bn2_b = (const float*)d_in[24];
    const float* w_bn2_m = (const float*)d_in[25];
    const float* w_bn2_v = (const float*)d_in[26];
    const float* w_w2    = (const float*)d_in[27];
    const float* w_b2    = (const float*)d_in[28];
    float* out = (float*)d_out;

    const int N = in_sizes[0] / 3;   // 65536

    u16* kvt = (u16*)d_ws;                       // N*128 bf16
    u16* qt  = (u16*)d_ws + (size_t)N * 128;     // N*64 bf16

    qkv_kernel<<<N / 128, 256, 0, stream>>>(feat, Wq, bq, Wk, bk, Wv, bv, qt, kvt);
    attn_kernel<<<N / 32, 256, 0, stream>>>(point, idx, qt, kvt,
                                            p_w1, p_b1, p_bn_g, p_bn_b, p_bn_m, p_bn_v, p_w2, p_b2,
                                            w_bn1_g, w_bn1_b, w_bn1_m, w_bn1_v, w_w1, w_b1,
                                            w_bn2_g, w_bn2_b, w_bn2_m, w_bn2_v, w_w2, w_b2,
                                            out);
}